// Round 9
// baseline (165.535 us; speedup 1.0000x reference)
//
#include <hip/hip_runtime.h>
#include <math.h>

#define B_ 32
#define S_ 4096
#define H_ 1024

// ---- pass1 geometry (R5-exact: best measured pass1) ----
#define RPB   64                // rows per block
#define NBLK  (S_ / RPB)        // 64 blocks per batch
#define RPW   16                // rows per wave

__device__ __forceinline__ float wave_reduce_sum(float v) {
    #pragma unroll
    for (int o = 32; o > 0; o >>= 1) v += __shfl_xor(v, o, 64);
    return v;
}

__device__ __forceinline__ void wave_reduce_sum2(float& a, float& b) {
    #pragma unroll
    for (int o = 32; o > 0; o >>= 1) {   // interleaved: the two chains pipeline
        a += __shfl_xor(a, o, 64);
        b += __shfl_xor(b, o, 64);
    }
}

// y[b*ystride + i0..i0+7] per wave; x cached in regs, W read exactly once.
__global__ __launch_bounds__(256) void gemv_aw(const float* __restrict__ x, int xstride,
                                               const float* __restrict__ W,
                                               const float* __restrict__ bias,
                                               float* __restrict__ y, int ystride) {
    int w = threadIdx.x >> 6, lane = threadIdx.x & 63;
    int gw = blockIdx.x * 4 + w;            // [0, B*128)
    int b = gw >> 7;
    int i0 = (gw & 127) << 3;
    const float4* xr = reinterpret_cast<const float4*>(x + (size_t)b * xstride);
    float4 xv[4];
    #pragma unroll
    for (int k = 0; k < 4; ++k) xv[k] = xr[lane + k * 64];
    #pragma unroll
    for (int j = 0; j < 8; j += 2) {
        const float4* w0 = reinterpret_cast<const float4*>(W + (size_t)(i0 + j) * H_);
        const float4* w1 = reinterpret_cast<const float4*>(W + (size_t)(i0 + j + 1) * H_);
        float s0 = 0.f, s1 = 0.f;
        #pragma unroll
        for (int k = 0; k < 4; ++k) {
            float4 a = w0[lane + k * 64], c = w1[lane + k * 64];
            s0 += a.x * xv[k].x + a.y * xv[k].y + a.z * xv[k].z + a.w * xv[k].w;
            s1 += c.x * xv[k].x + c.y * xv[k].y + c.z * xv[k].z + c.w * xv[k].w;
        }
        wave_reduce_sum2(s0, s1);
        if (lane == 0) {
            y[(size_t)b * ystride + i0 + j]     = s0 + bias[i0 + j];
            y[(size_t)b * ystride + i0 + j + 1] = s1 + bias[i0 + j + 1];
        }
    }
}

// loads two consecutive rows (local row index r, r+1) into d0/d1
#define LOADPAIR(d0, d1, r) do {                                                 \
    const float4* rp_ = base + (size_t)(r) * 256;                                \
    d0[0] = rp_[0]; d0[1] = rp_[64]; d0[2] = rp_[128]; d0[3] = rp_[192];         \
    const float4* rq_ = rp_ + 256;                                               \
    d1[0] = rq_[0]; d1[1] = rq_[64]; d1[2] = rq_[128]; d1[3] = rq_[192];         \
} while (0)

#define PROCESS(va, vb, lr) do {                                                 \
    float s0 = 0.f, s1 = 0.f;                                                    \
    _Pragma("unroll")                                                            \
    for (int k = 0; k < 4; ++k) {                                                \
        s0 += va[k].x * hv[k].x + va[k].y * hv[k].y + va[k].z * hv[k].z + va[k].w * hv[k].w; \
        s1 += vb[k].x * hv[k].x + vb[k].y * hv[k].y + vb[k].z * hv[k].z + vb[k].w * hv[k].w; \
    }                                                                            \
    wave_reduce_sum2(s0, s1);                                                    \
    my_score = (lane == (lr)    ) ? s0 : my_score;                               \
    my_score = (lane == (lr) + 1) ? s1 : my_score;                               \
    float tm_ = fmaxf(s0, s1);                                                   \
    if (tm_ > m) {                      /* wave-uniform, rare */                 \
        float sc_ = __expf(m - tm_);    /* m=-inf first time -> 0, exact */      \
        l *= sc_;                                                                \
        _Pragma("unroll")                                                        \
        for (int k = 0; k < 4; ++k) {                                            \
            acc[k].x *= sc_; acc[k].y *= sc_; acc[k].z *= sc_; acc[k].w *= sc_;  \
        }                                                                        \
        m = tm_;                                                                 \
    }                                                                            \
    float p0_ = __expf(s0 - m), p1_ = __expf(s1 - m);                            \
    l += p0_ + p1_;                                                              \
    _Pragma("unroll")                                                            \
    for (int k = 0; k < 4; ++k) {                                                \
        acc[k].x += p0_ * va[k].x + p1_ * vb[k].x;                               \
        acc[k].y += p0_ * va[k].y + p1_ * vb[k].y;                               \
        acc[k].z += p0_ * va[k].z + p1_ * vb[k].z;                               \
        acc[k].w += p0_ * va[k].w + p1_ * vb[k].w;                               \
    }                                                                            \
} while (0)

// Flash pass over enc. R5-exact: depth-2 register pipeline, contiguous slabs,
// (256,3) occupancy. Measured 143.9 total; pass1 ~4.6 TB/s (pattern ceiling).
__global__ __launch_bounds__(256, 3) void attn_pass1(const float* __restrict__ enc,
                                                     const float* __restrict__ h2,
                                                     float* __restrict__ scores,
                                                     float* __restrict__ partials) {
    int b   = blockIdx.x >> 6;              // NBLK = 64 blocks per batch
    int blk = blockIdx.x & (NBLK - 1);
    int w = threadIdx.x >> 6, lane = threadIdx.x & 63;

    int row0 = blk * RPB + w * RPW;
    const float4* base = reinterpret_cast<const float4*>(
        enc + (size_t)b * S_ * H_ + (size_t)row0 * H_) + lane;

    const float4* hp = reinterpret_cast<const float4*>(h2 + (size_t)b * H_);
    float4 hv[4];
    #pragma unroll
    for (int k = 0; k < 4; ++k) hv[k] = hp[lane + k * 64];

    float m = -INFINITY, l = 0.f;
    float4 acc[4];
    #pragma unroll
    for (int k = 0; k < 4; ++k) acc[k] = make_float4(0.f, 0.f, 0.f, 0.f);
    float my_score = 0.f;                   // lane r keeps local row r's score

    float4 A0[4], A1[4], B0[4], B1[4];
    LOADPAIR(A0, A1, 0);
    LOADPAIR(B0, B1, 2);

    #pragma unroll 1
    for (int t = 0; t < RPW; t += 4) {
        PROCESS(A0, A1, t);
        if (t + 4 < RPW) LOADPAIR(A0, A1, t + 4);
        PROCESS(B0, B1, t + 2);
        if (t + 6 < RPW) LOADPAIR(B0, B1, t + 6);
    }
    if (lane < RPW) scores[(size_t)b * S_ + row0 + lane] = my_score;

    // 4-wave merge in (small) LDS
    __shared__ float lds_ctx[4][H_];
    __shared__ float lds_m[4], lds_l[4];
    float4* mc = reinterpret_cast<float4*>(&lds_ctx[w][0]);
    #pragma unroll
    for (int k = 0; k < 4; ++k) mc[lane + k * 64] = acc[k];
    if (lane == 0) { lds_m[w] = m; lds_l[w] = l; }
    __syncthreads();

    float mb = fmaxf(fmaxf(lds_m[0], lds_m[1]), fmaxf(lds_m[2], lds_m[3]));
    float sc0 = __expf(lds_m[0] - mb), sc1 = __expf(lds_m[1] - mb);
    float sc2 = __expf(lds_m[2] - mb), sc3 = __expf(lds_m[3] - mb);
    float lb = lds_l[0] * sc0 + lds_l[1] * sc1 + lds_l[2] * sc2 + lds_l[3] * sc3;

    float* part = partials + ((size_t)b * NBLK + blk) * (H_ + 2);
    #pragma unroll
    for (int k2 = 0; k2 < 4; ++k2) {
        int col = threadIdx.x + k2 * 256;
        float v = lds_ctx[0][col] * sc0 + lds_ctx[1][col] * sc1 +
                  lds_ctx[2][col] * sc2 + lds_ctx[3][col] * sc3;
        part[2 + col] = v;
    }
    if (threadIdx.x == 0) { part[0] = mb; part[1] = lb; }
}

// per-batch reduce of NBLK=64 partials -> normalized context + fused attn write.
// grid = B*4 blocks; scale factors staged in LDS.
__global__ __launch_bounds__(256) void attn_reduce(const float* __restrict__ partials,
                                                   float* __restrict__ concat,
                                                   const float* __restrict__ scores,
                                                   float* __restrict__ attn_out) {
    int b = blockIdx.x >> 2;
    int q = blockIdx.x & 3;
    const float* part = partials + (size_t)b * NBLK * (H_ + 2);
    __shared__ float s_m[NBLK], s_l[NBLK], s_sc[NBLK];
    int t = threadIdx.x;
    if (t < NBLK) {
        s_m[t] = part[(size_t)t * (H_ + 2)];
        s_l[t] = part[(size_t)t * (H_ + 2) + 1];
    }
    __syncthreads();
    float mb = -INFINITY;
    #pragma unroll
    for (int k = 0; k < NBLK; ++k) mb = fmaxf(mb, s_m[k]);
    if (t < NBLK) s_sc[t] = __expf(s_m[t] - mb);
    __syncthreads();
    float lb = 0.f;
    #pragma unroll
    for (int k = 0; k < NBLK; ++k) lb += s_l[k] * s_sc[k];
    float inv_l = 1.f / lb;
    int col = q * 256 + t;
    float v = 0.f;
    #pragma unroll 8
    for (int k = 0; k < NBLK; ++k)
        v += part[(size_t)k * (H_ + 2) + 2 + col] * s_sc[k];
    concat[(size_t)b * 2048 + 1024 + col] = v * inv_l;

    // fused attn-weight write: this block's quarter of scores[b,:]
    const float4* sp = reinterpret_cast<const float4*>(scores + (size_t)b * S_ + q * 1024);
    float4* ap = reinterpret_cast<float4*>(attn_out + (size_t)b * S_ + q * 1024);
    float4 sv = sp[t];
    float4 av;
    av.x = __expf(sv.x - mb) * inv_l;
    av.y = __expf(sv.y - mb) * inv_l;
    av.z = __expf(sv.z - mb) * inv_l;
    av.w = __expf(sv.w - mb) * inv_l;
    ap[t] = av;
}

// out[b,i] = tanh(dot(concat[b,:], Cw[i,:]) + Cb[i])
// 128 blocks x 8 i's (2 per wave, Cw rows in VGPRs), loop over 32 batches:
// concat L3 traffic = 128 blocks * 256 KB = 32 MB (was 256 MB at 1024 blocks).
__global__ __launch_bounds__(256) void out_gemm(const float* __restrict__ concat,
                                                const float* __restrict__ Cw,
                                                const float* __restrict__ Cb,
                                                float* __restrict__ out) {
    int w = threadIdx.x >> 6, lane = threadIdx.x & 63;
    int i0 = blockIdx.x * 8 + w * 2;
    const float4* w0 = reinterpret_cast<const float4*>(Cw + (size_t)i0 * 2048);
    const float4* w1 = reinterpret_cast<const float4*>(Cw + (size_t)(i0 + 1) * 2048);
    float4 wv0[8], wv1[8];
    #pragma unroll
    for (int k = 0; k < 8; ++k) { wv0[k] = w0[lane + k * 64]; wv1[k] = w1[lane + k * 64]; }
    float b0 = Cb[i0], b1 = Cb[i0 + 1];
    #pragma unroll 1
    for (int b = 0; b < B_; ++b) {
        const float4* cr = reinterpret_cast<const float4*>(concat + (size_t)b * 2048);
        float s0 = 0.f, s1 = 0.f;
        #pragma unroll
        for (int k = 0; k < 8; ++k) {
            float4 c = cr[lane + k * 64];
            s0 += c.x * wv0[k].x + c.y * wv0[k].y + c.z * wv0[k].z + c.w * wv0[k].w;
            s1 += c.x * wv1[k].x + c.y * wv1[k].y + c.z * wv1[k].z + c.w * wv1[k].w;
        }
        wave_reduce_sum2(s0, s1);
        if (lane == 0) {
            out[(size_t)b * H_ + i0]     = tanhf(s0 + b0);
            out[(size_t)b * H_ + i0 + 1] = tanhf(s1 + b1);
        }
    }
}

extern "C" void kernel_launch(void* const* d_in, const int* in_sizes, int n_in,
                              void* d_out, int out_size, void* d_ws, size_t ws_size,
                              hipStream_t stream) {
    const float* hs  = (const float*)d_in[0];   // [B,1,H]
    const float* enc = (const float*)d_in[1];   // [B,S,H]
    const float* A_w = (const float*)d_in[2];   // [H,H]
    const float* A_b = (const float*)d_in[3];   // [H]
    const float* C_w = (const float*)d_in[4];   // [H,2H]
    const float* C_b = (const float*)d_in[5];   // [H]

    float* out      = (float*)d_out;            // [B,H] first
    float* attn_out = out + B_ * H_;            // then [B,S,1]

    // workspace layout (floats)
    float* ws       = (float*)d_ws;
    float* concat   = ws;                                   // [B][2048]: h1 | ctx
    float* h2       = ws + (size_t)B_ * 2048;               // [B][1024]
    float* scores   = h2 + (size_t)B_ * H_;                 // [B][S]
    float* partials = scores + (size_t)B_ * S_;             // [B][NBLK][H+2]

    gemv_aw<<<(B_ * H_) / 32, 256, 0, stream>>>(hs, H_, A_w, A_b, concat, 2048);
    gemv_aw<<<(B_ * H_) / 32, 256, 0, stream>>>(concat, 2048, A_w, A_b, h2, H_);
    attn_pass1<<<B_ * NBLK, 256, 0, stream>>>(enc, h2, scores, partials);
    attn_reduce<<<B_ * 4, 256, 0, stream>>>(partials, concat, scores, attn_out);
    out_gemm<<<H_ / 8, 256, 0, stream>>>(concat, C_w, C_b, out);
}

// Round 10
// 129.850 us; speedup vs baseline: 1.2748x; 1.2748x over previous
//
#include <hip/hip_runtime.h>
#include <math.h>

#define B_ 32
#define S_ 4096
#define H_ 1024

// ---- pass1 geometry (R5-exact: best measured pass1) ----
#define RPB   64                // rows per block
#define NBLK  (S_ / RPB)        // 64 blocks per batch
#define RPW   16                // rows per wave

typedef float f32x4 __attribute__((ext_vector_type(4)));
__device__ __forceinline__ float4 ntload(const float4* p) {
    f32x4 v = __builtin_nontemporal_load(reinterpret_cast<const f32x4*>(p));
    union { f32x4 a; float4 b; } u; u.a = v; return u.b;
}

__device__ __forceinline__ float wave_reduce_sum(float v) {
    #pragma unroll
    for (int o = 32; o > 0; o >>= 1) v += __shfl_xor(v, o, 64);
    return v;
}

__device__ __forceinline__ void wave_reduce_sum2(float& a, float& b) {
    #pragma unroll
    for (int o = 32; o > 0; o >>= 1) {   // interleaved: the two chains pipeline
        a += __shfl_xor(a, o, 64);
        b += __shfl_xor(b, o, 64);
    }
}

// y[b*ystride + i0..i0+7] per wave; x cached in regs, W read exactly once.
__global__ __launch_bounds__(256) void gemv_aw(const float* __restrict__ x, int xstride,
                                               const float* __restrict__ W,
                                               const float* __restrict__ bias,
                                               float* __restrict__ y, int ystride) {
    int w = threadIdx.x >> 6, lane = threadIdx.x & 63;
    int gw = blockIdx.x * 4 + w;            // [0, B*128)
    int b = gw >> 7;
    int i0 = (gw & 127) << 3;
    const float4* xr = reinterpret_cast<const float4*>(x + (size_t)b * xstride);
    float4 xv[4];
    #pragma unroll
    for (int k = 0; k < 4; ++k) xv[k] = xr[lane + k * 64];
    #pragma unroll
    for (int j = 0; j < 8; j += 2) {
        const float4* w0 = reinterpret_cast<const float4*>(W + (size_t)(i0 + j) * H_);
        const float4* w1 = reinterpret_cast<const float4*>(W + (size_t)(i0 + j + 1) * H_);
        float s0 = 0.f, s1 = 0.f;
        #pragma unroll
        for (int k = 0; k < 4; ++k) {
            float4 a = w0[lane + k * 64], c = w1[lane + k * 64];
            s0 += a.x * xv[k].x + a.y * xv[k].y + a.z * xv[k].z + a.w * xv[k].w;
            s1 += c.x * xv[k].x + c.y * xv[k].y + c.z * xv[k].z + c.w * xv[k].w;
        }
        wave_reduce_sum2(s0, s1);
        if (lane == 0) {
            y[(size_t)b * ystride + i0 + j]     = s0 + bias[i0 + j];
            y[(size_t)b * ystride + i0 + j + 1] = s1 + bias[i0 + j + 1];
        }
    }
}

// loads two consecutive rows (local row index r, r+1) into d0/d1 — NT variant
#define LOADPAIR(d0, d1, r) do {                                                 \
    const float4* rp_ = base + (size_t)(r) * 256;                                \
    d0[0] = ntload(rp_);       d0[1] = ntload(rp_ + 64);                         \
    d0[2] = ntload(rp_ + 128); d0[3] = ntload(rp_ + 192);                        \
    const float4* rq_ = rp_ + 256;                                               \
    d1[0] = ntload(rq_);       d1[1] = ntload(rq_ + 64);                         \
    d1[2] = ntload(rq_ + 128); d1[3] = ntload(rq_ + 192);                        \
} while (0)

#define PROCESS(va, vb, lr) do {                                                 \
    float s0 = 0.f, s1 = 0.f;                                                    \
    _Pragma("unroll")                                                            \
    for (int k = 0; k < 4; ++k) {                                                \
        s0 += va[k].x * hv[k].x + va[k].y * hv[k].y + va[k].z * hv[k].z + va[k].w * hv[k].w; \
        s1 += vb[k].x * hv[k].x + vb[k].y * hv[k].y + vb[k].z * hv[k].z + vb[k].w * hv[k].w; \
    }                                                                            \
    wave_reduce_sum2(s0, s1);                                                    \
    my_score = (lane == (lr)    ) ? s0 : my_score;                               \
    my_score = (lane == (lr) + 1) ? s1 : my_score;                               \
    float tm_ = fmaxf(s0, s1);                                                   \
    if (tm_ > m) {                      /* wave-uniform, rare */                 \
        float sc_ = __expf(m - tm_);    /* m=-inf first time -> 0, exact */      \
        l *= sc_;                                                                \
        _Pragma("unroll")                                                        \
        for (int k = 0; k < 4; ++k) {                                            \
            acc[k].x *= sc_; acc[k].y *= sc_; acc[k].z *= sc_; acc[k].w *= sc_;  \
        }                                                                        \
        m = tm_;                                                                 \
    }                                                                            \
    float p0_ = __expf(s0 - m), p1_ = __expf(s1 - m);                            \
    l += p0_ + p1_;                                                              \
    _Pragma("unroll")                                                            \
    for (int k = 0; k < 4; ++k) {                                                \
        acc[k].x += p0_ * va[k].x + p1_ * vb[k].x;                               \
        acc[k].y += p0_ * va[k].y + p1_ * vb[k].y;                               \
        acc[k].z += p0_ * va[k].z + p1_ * vb[k].z;                               \
        acc[k].w += p0_ * va[k].w + p1_ * vb[k].w;                               \
    }                                                                            \
} while (0)

// Flash pass over enc. R5-exact schedule (depth-2 register pipeline, contiguous
// slabs, (256,3)); ONLY change vs R5: nontemporal enc loads (no L2 retention
// for the 512MB zero-reuse stream; R6 only tested nt confounded with striding).
__global__ __launch_bounds__(256, 3) void attn_pass1(const float* __restrict__ enc,
                                                     const float* __restrict__ h2,
                                                     float* __restrict__ scores,
                                                     float* __restrict__ partials) {
    int b   = blockIdx.x >> 6;              // NBLK = 64 blocks per batch
    int blk = blockIdx.x & (NBLK - 1);
    int w = threadIdx.x >> 6, lane = threadIdx.x & 63;

    int row0 = blk * RPB + w * RPW;
    const float4* base = reinterpret_cast<const float4*>(
        enc + (size_t)b * S_ * H_ + (size_t)row0 * H_) + lane;

    const float4* hp = reinterpret_cast<const float4*>(h2 + (size_t)b * H_);
    float4 hv[4];
    #pragma unroll
    for (int k = 0; k < 4; ++k) hv[k] = hp[lane + k * 64];

    float m = -INFINITY, l = 0.f;
    float4 acc[4];
    #pragma unroll
    for (int k = 0; k < 4; ++k) acc[k] = make_float4(0.f, 0.f, 0.f, 0.f);
    float my_score = 0.f;                   // lane r keeps local row r's score

    float4 A0[4], A1[4], B0[4], B1[4];
    LOADPAIR(A0, A1, 0);
    LOADPAIR(B0, B1, 2);

    #pragma unroll 1
    for (int t = 0; t < RPW; t += 4) {
        PROCESS(A0, A1, t);
        if (t + 4 < RPW) LOADPAIR(A0, A1, t + 4);
        PROCESS(B0, B1, t + 2);
        if (t + 6 < RPW) LOADPAIR(B0, B1, t + 6);
    }
    if (lane < RPW) scores[(size_t)b * S_ + row0 + lane] = my_score;

    // 4-wave merge in (small) LDS
    __shared__ float lds_ctx[4][H_];
    __shared__ float lds_m[4], lds_l[4];
    float4* mc = reinterpret_cast<float4*>(&lds_ctx[w][0]);
    #pragma unroll
    for (int k = 0; k < 4; ++k) mc[lane + k * 64] = acc[k];
    if (lane == 0) { lds_m[w] = m; lds_l[w] = l; }
    __syncthreads();

    float mb = fmaxf(fmaxf(lds_m[0], lds_m[1]), fmaxf(lds_m[2], lds_m[3]));
    float sc0 = __expf(lds_m[0] - mb), sc1 = __expf(lds_m[1] - mb);
    float sc2 = __expf(lds_m[2] - mb), sc3 = __expf(lds_m[3] - mb);
    float lb = lds_l[0] * sc0 + lds_l[1] * sc1 + lds_l[2] * sc2 + lds_l[3] * sc3;

    float* part = partials + ((size_t)b * NBLK + blk) * (H_ + 2);
    #pragma unroll
    for (int k2 = 0; k2 < 4; ++k2) {
        int col = threadIdx.x + k2 * 256;
        float v = lds_ctx[0][col] * sc0 + lds_ctx[1][col] * sc1 +
                  lds_ctx[2][col] * sc2 + lds_ctx[3][col] * sc3;
        part[2 + col] = v;
    }
    if (threadIdx.x == 0) { part[0] = mb; part[1] = lb; }
}

// per-batch reduce of NBLK=64 partials -> normalized context + fused attn write.
// grid = B*4 blocks; scale factors staged in LDS.
__global__ __launch_bounds__(256) void attn_reduce(const float* __restrict__ partials,
                                                   float* __restrict__ concat,
                                                   const float* __restrict__ scores,
                                                   float* __restrict__ attn_out) {
    int b = blockIdx.x >> 2;
    int q = blockIdx.x & 3;
    const float* part = partials + (size_t)b * NBLK * (H_ + 2);
    __shared__ float s_m[NBLK], s_l[NBLK], s_sc[NBLK];
    int t = threadIdx.x;
    if (t < NBLK) {
        s_m[t] = part[(size_t)t * (H_ + 2)];
        s_l[t] = part[(size_t)t * (H_ + 2) + 1];
    }
    __syncthreads();
    float mb = -INFINITY;
    #pragma unroll
    for (int k = 0; k < NBLK; ++k) mb = fmaxf(mb, s_m[k]);
    if (t < NBLK) s_sc[t] = __expf(s_m[t] - mb);
    __syncthreads();
    float lb = 0.f;
    #pragma unroll
    for (int k = 0; k < NBLK; ++k) lb += s_l[k] * s_sc[k];
    float inv_l = 1.f / lb;
    int col = q * 256 + t;
    float v = 0.f;
    #pragma unroll 8
    for (int k = 0; k < NBLK; ++k)
        v += part[(size_t)k * (H_ + 2) + 2 + col] * s_sc[k];
    concat[(size_t)b * 2048 + 1024 + col] = v * inv_l;

    // fused attn-weight write: this block's quarter of scores[b,:]
    const float4* sp = reinterpret_cast<const float4*>(scores + (size_t)b * S_ + q * 1024);
    float4* ap = reinterpret_cast<float4*>(attn_out + (size_t)b * S_ + q * 1024);
    float4 sv = sp[t];
    float4 av;
    av.x = __expf(sv.x - mb) * inv_l;
    av.y = __expf(sv.y - mb) * inv_l;
    av.z = __expf(sv.z - mb) * inv_l;
    av.w = __expf(sv.w - mb) * inv_l;
    ap[t] = av;
}

// out[b,i] = tanh(dot(concat[b,:], Cw[i,:]) + Cb[i])
// R5-exact: one block per i (1024 blocks); 4 waves x 8 batches (concat L2-hot).
// R9 proved the 128-block variant is latency-bound and ~10-20us slower.
__global__ __launch_bounds__(256) void out_gemm(const float* __restrict__ concat,
                                                const float* __restrict__ Cw,
                                                const float* __restrict__ Cb,
                                                float* __restrict__ out) {
    int w = threadIdx.x >> 6, lane = threadIdx.x & 63;
    int i = blockIdx.x;
    const float4* wr = reinterpret_cast<const float4*>(Cw + (size_t)i * 2048);
    float4 wv[8];
    #pragma unroll
    for (int k = 0; k < 8; ++k) wv[k] = wr[lane + k * 64];
    float bias = Cb[i];
    #pragma unroll
    for (int bb = 0; bb < 8; ++bb) {
        int b = w * 8 + bb;
        const float4* cr = reinterpret_cast<const float4*>(concat + (size_t)b * 2048);
        float s = 0.f;
        #pragma unroll
        for (int k = 0; k < 8; ++k) {
            float4 c = cr[lane + k * 64];
            s += c.x * wv[k].x + c.y * wv[k].y + c.z * wv[k].z + c.w * wv[k].w;
        }
        s = wave_reduce_sum(s);
        if (lane == 0) out[(size_t)b * H_ + i] = tanhf(s + bias);
    }
}

extern "C" void kernel_launch(void* const* d_in, const int* in_sizes, int n_in,
                              void* d_out, int out_size, void* d_ws, size_t ws_size,
                              hipStream_t stream) {
    const float* hs  = (const float*)d_in[0];   // [B,1,H]
    const float* enc = (const float*)d_in[1];   // [B,S,H]
    const float* A_w = (const float*)d_in[2];   // [H,H]
    const float* A_b = (const float*)d_in[3];   // [H]
    const float* C_w = (const float*)d_in[4];   // [H,2H]
    const float* C_b = (const float*)d_in[5];   // [H]

    float* out      = (float*)d_out;            // [B,H] first
    float* attn_out = out + B_ * H_;            // then [B,S,1]

    // workspace layout (floats)
    float* ws       = (float*)d_ws;
    float* concat   = ws;                                   // [B][2048]: h1 | ctx
    float* h2       = ws + (size_t)B_ * 2048;               // [B][1024]
    float* scores   = h2 + (size_t)B_ * H_;                 // [B][S]
    float* partials = scores + (size_t)B_ * S_;             // [B][NBLK][H+2]

    gemv_aw<<<(B_ * H_) / 32, 256, 0, stream>>>(hs, H_, A_w, A_b, concat, 2048);
    gemv_aw<<<(B_ * H_) / 32, 256, 0, stream>>>(concat, 2048, A_w, A_b, h2, H_);
    attn_pass1<<<B_ * NBLK, 256, 0, stream>>>(enc, h2, scores, partials);
    attn_reduce<<<B_ * 4, 256, 0, stream>>>(partials, concat, scores, attn_out);
    out_gemm<<<H_, 256, 0, stream>>>(concat, C_w, C_b, out);
}

// Round 11
// 128.914 us; speedup vs baseline: 1.2841x; 1.0073x over previous
//
#include <hip/hip_runtime.h>
#include <math.h>

#define B_ 32
#define S_ 4096
#define H_ 1024

// ---- pass1 geometry ----
#define RPB   64                // rows per block
#define NBLK  (S_ / RPB)        // 64 blocks per batch
#define RPW   16                // rows per wave

typedef float f32x4 __attribute__((ext_vector_type(4)));
__device__ __forceinline__ float4 ntload(const float4* p) {
    f32x4 v = __builtin_nontemporal_load(reinterpret_cast<const f32x4*>(p));
    union { f32x4 a; float4 b; } u; u.a = v; return u.b;
}

__device__ __forceinline__ float wave_reduce_sum(float v) {
    #pragma unroll
    for (int o = 32; o > 0; o >>= 1) v += __shfl_xor(v, o, 64);
    return v;
}

__device__ __forceinline__ void wave_reduce_sum2(float& a, float& b) {
    #pragma unroll
    for (int o = 32; o > 0; o >>= 1) {   // interleaved: the two chains pipeline
        a += __shfl_xor(a, o, 64);
        b += __shfl_xor(b, o, 64);
    }
}

// y[b*ystride + i0..i0+7] per wave; x cached in regs, W read exactly once.
__global__ __launch_bounds__(256) void gemv_aw(const float* __restrict__ x, int xstride,
                                               const float* __restrict__ W,
                                               const float* __restrict__ bias,
                                               float* __restrict__ y, int ystride) {
    int w = threadIdx.x >> 6, lane = threadIdx.x & 63;
    int gw = blockIdx.x * 4 + w;            // [0, B*128)
    int b = gw >> 7;
    int i0 = (gw & 127) << 3;
    const float4* xr = reinterpret_cast<const float4*>(x + (size_t)b * xstride);
    float4 xv[4];
    #pragma unroll
    for (int k = 0; k < 4; ++k) xv[k] = xr[lane + k * 64];
    #pragma unroll
    for (int j = 0; j < 8; j += 2) {
        const float4* w0 = reinterpret_cast<const float4*>(W + (size_t)(i0 + j) * H_);
        const float4* w1 = reinterpret_cast<const float4*>(W + (size_t)(i0 + j + 1) * H_);
        float s0 = 0.f, s1 = 0.f;
        #pragma unroll
        for (int k = 0; k < 4; ++k) {
            float4 a = w0[lane + k * 64], c = w1[lane + k * 64];
            s0 += a.x * xv[k].x + a.y * xv[k].y + a.z * xv[k].z + a.w * xv[k].w;
            s1 += c.x * xv[k].x + c.y * xv[k].y + c.z * xv[k].z + c.w * xv[k].w;
        }
        wave_reduce_sum2(s0, s1);
        if (lane == 0) {
            y[(size_t)b * ystride + i0 + j]     = s0 + bias[i0 + j];
            y[(size_t)b * ystride + i0 + j + 1] = s1 + bias[i0 + j + 1];
        }
    }
}

// loads two consecutive rows (local row index r, r+1) into d0/d1 — NT variant
#define LOADPAIR(d0, d1, r) do {                                                 \
    const float4* rp_ = base + (size_t)(r) * 256;                                \
    d0[0] = ntload(rp_);       d0[1] = ntload(rp_ + 64);                         \
    d0[2] = ntload(rp_ + 128); d0[3] = ntload(rp_ + 192);                        \
    const float4* rq_ = rp_ + 256;                                               \
    d1[0] = ntload(rq_);       d1[1] = ntload(rq_ + 64);                         \
    d1[2] = ntload(rq_ + 128); d1[3] = ntload(rq_ + 192);                        \
} while (0)

#define PROCESS(va, vb, lr) do {                                                 \
    float s0 = 0.f, s1 = 0.f;                                                    \
    _Pragma("unroll")                                                            \
    for (int k = 0; k < 4; ++k) {                                                \
        s0 += va[k].x * hv[k].x + va[k].y * hv[k].y + va[k].z * hv[k].z + va[k].w * hv[k].w; \
        s1 += vb[k].x * hv[k].x + vb[k].y * hv[k].y + vb[k].z * hv[k].z + vb[k].w * hv[k].w; \
    }                                                                            \
    wave_reduce_sum2(s0, s1);                                                    \
    my_score = (lane == (lr)    ) ? s0 : my_score;                               \
    my_score = (lane == (lr) + 1) ? s1 : my_score;                               \
    float tm_ = fmaxf(s0, s1);                                                   \
    if (tm_ > m) {                      /* wave-uniform, rare */                 \
        float sc_ = __expf(m - tm_);    /* m=-inf first time -> 0, exact */      \
        l *= sc_;                                                                \
        _Pragma("unroll")                                                        \
        for (int k = 0; k < 4; ++k) {                                            \
            acc[k].x *= sc_; acc[k].y *= sc_; acc[k].z *= sc_; acc[k].w *= sc_;  \
        }                                                                        \
        m = tm_;                                                                 \
    }                                                                            \
    float p0_ = __expf(s0 - m), p1_ = __expf(s1 - m);                            \
    l += p0_ + p1_;                                                              \
    _Pragma("unroll")                                                            \
    for (int k = 0; k < 4; ++k) {                                                \
        acc[k].x += p0_ * va[k].x + p1_ * vb[k].x;                               \
        acc[k].y += p0_ * va[k].y + p1_ * vb[k].y;                               \
        acc[k].z += p0_ * va[k].z + p1_ * vb[k].z;                               \
        acc[k].w += p0_ * va[k].w + p1_ * vb[k].w;                               \
    }                                                                            \
} while (0)

// Flash pass over enc. R10 + ONE change: depth-3 prefetch (3 named pair-buffers
// rotated A,B,C over 8 statically-unrolled pairs). Post-nt, load latency is the
// ~900cy HBM figure; depth-2's ~1-PROCESS (~500cy) distance under-covered it.
// ~150 live VGPRs < 168 cap at (256,3): no spill, 12 waves/CU.
__global__ __launch_bounds__(256, 3) void attn_pass1(const float* __restrict__ enc,
                                                     const float* __restrict__ h2,
                                                     float* __restrict__ scores,
                                                     float* __restrict__ partials) {
    int b   = blockIdx.x >> 6;              // NBLK = 64 blocks per batch
    int blk = blockIdx.x & (NBLK - 1);
    int w = threadIdx.x >> 6, lane = threadIdx.x & 63;

    int row0 = blk * RPB + w * RPW;
    const float4* base = reinterpret_cast<const float4*>(
        enc + (size_t)b * S_ * H_ + (size_t)row0 * H_) + lane;

    const float4* hp = reinterpret_cast<const float4*>(h2 + (size_t)b * H_);
    float4 hv[4];
    #pragma unroll
    for (int k = 0; k < 4; ++k) hv[k] = hp[lane + k * 64];

    float m = -INFINITY, l = 0.f;
    float4 acc[4];
    #pragma unroll
    for (int k = 0; k < 4; ++k) acc[k] = make_float4(0.f, 0.f, 0.f, 0.f);
    float my_score = 0.f;                   // lane r keeps local row r's score

    float4 A0[4], A1[4], B0[4], B1[4], C0[4], C1[4];
    LOADPAIR(A0, A1, 0);
    LOADPAIR(B0, B1, 2);
    LOADPAIR(C0, C1, 4);

    PROCESS(A0, A1, 0);   LOADPAIR(A0, A1, 6);
    PROCESS(B0, B1, 2);   LOADPAIR(B0, B1, 8);
    PROCESS(C0, C1, 4);   LOADPAIR(C0, C1, 10);
    PROCESS(A0, A1, 6);   LOADPAIR(A0, A1, 12);
    PROCESS(B0, B1, 8);   LOADPAIR(B0, B1, 14);
    PROCESS(C0, C1, 10);
    PROCESS(A0, A1, 12);
    PROCESS(B0, B1, 14);

    if (lane < RPW) scores[(size_t)b * S_ + row0 + lane] = my_score;

    // 4-wave merge in (small) LDS
    __shared__ float lds_ctx[4][H_];
    __shared__ float lds_m[4], lds_l[4];
    float4* mc = reinterpret_cast<float4*>(&lds_ctx[w][0]);
    #pragma unroll
    for (int k = 0; k < 4; ++k) mc[lane + k * 64] = acc[k];
    if (lane == 0) { lds_m[w] = m; lds_l[w] = l; }
    __syncthreads();

    float mb = fmaxf(fmaxf(lds_m[0], lds_m[1]), fmaxf(lds_m[2], lds_m[3]));
    float sc0 = __expf(lds_m[0] - mb), sc1 = __expf(lds_m[1] - mb);
    float sc2 = __expf(lds_m[2] - mb), sc3 = __expf(lds_m[3] - mb);
    float lb = lds_l[0] * sc0 + lds_l[1] * sc1 + lds_l[2] * sc2 + lds_l[3] * sc3;

    float* part = partials + ((size_t)b * NBLK + blk) * (H_ + 2);
    #pragma unroll
    for (int k2 = 0; k2 < 4; ++k2) {
        int col = threadIdx.x + k2 * 256;
        float v = lds_ctx[0][col] * sc0 + lds_ctx[1][col] * sc1 +
                  lds_ctx[2][col] * sc2 + lds_ctx[3][col] * sc3;
        part[2 + col] = v;
    }
    if (threadIdx.x == 0) { part[0] = mb; part[1] = lb; }
}

// per-batch reduce of NBLK=64 partials -> normalized context + fused attn write.
// grid = B*4 blocks; scale factors staged in LDS.
__global__ __launch_bounds__(256) void attn_reduce(const float* __restrict__ partials,
                                                   float* __restrict__ concat,
                                                   const float* __restrict__ scores,
                                                   float* __restrict__ attn_out) {
    int b = blockIdx.x >> 2;
    int q = blockIdx.x & 3;
    const float* part = partials + (size_t)b * NBLK * (H_ + 2);
    __shared__ float s_m[NBLK], s_l[NBLK], s_sc[NBLK];
    int t = threadIdx.x;
    if (t < NBLK) {
        s_m[t] = part[(size_t)t * (H_ + 2)];
        s_l[t] = part[(size_t)t * (H_ + 2) + 1];
    }
    __syncthreads();
    float mb = -INFINITY;
    #pragma unroll
    for (int k = 0; k < NBLK; ++k) mb = fmaxf(mb, s_m[k]);
    if (t < NBLK) s_sc[t] = __expf(s_m[t] - mb);
    __syncthreads();
    float lb = 0.f;
    #pragma unroll
    for (int k = 0; k < NBLK; ++k) lb += s_l[k] * s_sc[k];
    float inv_l = 1.f / lb;
    int col = q * 256 + t;
    float v = 0.f;
    #pragma unroll 8
    for (int k = 0; k < NBLK; ++k)
        v += part[(size_t)k * (H_ + 2) + 2 + col] * s_sc[k];
    concat[(size_t)b * 2048 + 1024 + col] = v * inv_l;

    // fused attn-weight write: this block's quarter of scores[b,:]
    const float4* sp = reinterpret_cast<const float4*>(scores + (size_t)b * S_ + q * 1024);
    float4* ap = reinterpret_cast<float4*>(attn_out + (size_t)b * S_ + q * 1024);
    float4 sv = sp[t];
    float4 av;
    av.x = __expf(sv.x - mb) * inv_l;
    av.y = __expf(sv.y - mb) * inv_l;
    av.z = __expf(sv.z - mb) * inv_l;
    av.w = __expf(sv.w - mb) * inv_l;
    ap[t] = av;
}

// out[b,i] = tanh(dot(concat[b,:], Cw[i,:]) + Cb[i])
// One block per i (1024 blocks); 4 waves x 8 batches (concat L2-hot).
__global__ __launch_bounds__(256) void out_gemm(const float* __restrict__ concat,
                                                const float* __restrict__ Cw,
                                                const float* __restrict__ Cb,
                                                float* __restrict__ out) {
    int w = threadIdx.x >> 6, lane = threadIdx.x & 63;
    int i = blockIdx.x;
    const float4* wr = reinterpret_cast<const float4*>(Cw + (size_t)i * 2048);
    float4 wv[8];
    #pragma unroll
    for (int k = 0; k < 8; ++k) wv[k] = wr[lane + k * 64];
    float bias = Cb[i];
    #pragma unroll
    for (int bb = 0; bb < 8; ++bb) {
        int b = w * 8 + bb;
        const float4* cr = reinterpret_cast<const float4*>(concat + (size_t)b * 2048);
        float s = 0.f;
        #pragma unroll
        for (int k = 0; k < 8; ++k) {
            float4 c = cr[lane + k * 64];
            s += c.x * wv[k].x + c.y * wv[k].y + c.z * wv[k].z + c.w * wv[k].w;
        }
        s = wave_reduce_sum(s);
        if (lane == 0) out[(size_t)b * H_ + i] = tanhf(s + bias);
    }
}

extern "C" void kernel_launch(void* const* d_in, const int* in_sizes, int n_in,
                              void* d_out, int out_size, void* d_ws, size_t ws_size,
                              hipStream_t stream) {
    const float* hs  = (const float*)d_in[0];   // [B,1,H]
    const float* enc = (const float*)d_in[1];   // [B,S,H]
    const float* A_w = (const float*)d_in[2];   // [H,H]
    const float* A_b = (const float*)d_in[3];   // [H]
    const float* C_w = (const float*)d_in[4];   // [H,2H]
    const float* C_b = (const float*)d_in[5];   // [H]

    float* out      = (float*)d_out;            // [B,H] first
    float* attn_out = out + B_ * H_;            // then [B,S,1]

    // workspace layout (floats)
    float* ws       = (float*)d_ws;
    float* concat   = ws;                                   // [B][2048]: h1 | ctx
    float* h2       = ws + (size_t)B_ * 2048;               // [B][1024]
    float* scores   = h2 + (size_t)B_ * H_;                 // [B][S]
    float* partials = scores + (size_t)B_ * S_;             // [B][NBLK][H+2]

    gemv_aw<<<(B_ * H_) / 32, 256, 0, stream>>>(hs, H_, A_w, A_b, concat, 2048);
    gemv_aw<<<(B_ * H_) / 32, 256, 0, stream>>>(concat, 2048, A_w, A_b, h2, H_);
    attn_pass1<<<B_ * NBLK, 256, 0, stream>>>(enc, h2, scores, partials);
    attn_reduce<<<B_ * 4, 256, 0, stream>>>(partials, concat, scores, attn_out);
    out_gemm<<<H_, 256, 0, stream>>>(concat, C_w, C_b, out);
}